// Round 11
// baseline (2256.837 us; speedup 1.0000x reference)
//
#include <hip/hip_runtime.h>
#include <hip/hip_bf16.h>

#define GB 2  // batch elems per convB block

__device__ __forceinline__ float elu1(float v) { return v > 0.f ? v : expm1f(v); }

// ---------------- cnorm: ||cb_k||^2 per code ----------------
__global__ void cnorm_kernel(const float* __restrict__ cb, float* __restrict__ cnorm) {
    int g = blockIdx.x * blockDim.x + threadIdx.x;  // 0..8191  (q*1024+k)
    if (g >= 8 * 1024) return;
    const float* p = cb + (size_t)g * 256;
    float s = 0.f;
    for (int d = 0; d < 256; d += 4) {
        float4 v = *reinterpret_cast<const float4*>(p + d);
        s += v.x * v.x + v.y * v.y + v.z * v.z + v.w * v.w;
    }
    cnorm[g] = s;
}

// ---------------- cbtrans: codebook -> stage-major layout -------------------
// cbT[(s*8 + dl)*1024 + k] = cb[((s>>5)*1024 + k)*256 + (s&31)*8 + dl]
__global__ void cbtrans_kernel(const float* __restrict__ cb, float* __restrict__ cbT) {
    int t = blockIdx.x * blockDim.x + threadIdx.x;  // 0..524287 (float4 units)
    int o = t * 4;
    const int s = o >> 13;          // stage 0..255
    const int r = o & 8191;
    const int dl = r >> 10;
    const int k = r & 1023;         // k..k+3
    const int q = s >> 5;
    const int d = (s & 31) * 8 + dl;
    const float* src = cb + ((size_t)(q * 1024 + k)) * 256 + d;
    float4 v;
    v.x = src[0 * 256]; v.y = src[1 * 256]; v.z = src[2 * 256]; v.w = src[3 * 256];
    *reinterpret_cast<float4*>(cbT + o) = v;
}

// ---------------- weight transpose to lane-major layouts ----------------
// W1T[(ci*128 + c)*8 + k]                          (ci<64,  c<128, k<8)
// W2T[(ci*256 + c)*12 + j], j<10, pad 2            (ci<128, c<256)
// W3T[(ci*256 + c)*8 + jj], jj<6 = taps 6..11, pad 2 (ci<256, c<256)
__global__ void wtrans_kernel(const float* __restrict__ W1, const float* __restrict__ W2,
                              const float* __restrict__ W3, float* __restrict__ W1T,
                              float* __restrict__ W2T, float* __restrict__ W3T) {
    int g = blockIdx.x * blockDim.x + threadIdx.x;
    if (g < 8192) {  // W1
        int ci = g >> 7, c = g & 127;
        const float* src = W1 + c * 512 + ci * 8;
        float4 a = *reinterpret_cast<const float4*>(src);
        float4 b = *reinterpret_cast<const float4*>(src + 4);
        *reinterpret_cast<float4*>(W1T + g * 8) = a;
        *reinterpret_cast<float4*>(W1T + g * 8 + 4) = b;
    }
    int g2 = g - 8192;
    if (g2 >= 0 && g2 < 32768) {  // W2
        int ci = g2 >> 8, c = g2 & 255;
        const float* src = W2 + c * 1280 + ci * 10;
        float* dst = W2T + g2 * 12;
#pragma unroll
        for (int j = 0; j < 5; ++j)
            *reinterpret_cast<float2*>(dst + 2 * j) =
                *reinterpret_cast<const float2*>(src + 2 * j);
        dst[10] = 0.f; dst[11] = 0.f;
    }
    int g3 = g - 40960;
    if (g3 >= 0 && g3 < 65536) {  // W3 (only taps 6..11 are ever used)
        int ci = g3 >> 8, c = g3 & 255;
        const float* src = W3 + c * 3072 + ci * 12 + 6;
        float* dst = W3T + g3 * 8;
#pragma unroll
        for (int j = 0; j < 3; ++j)
            *reinterpret_cast<float2*>(dst + 2 * j) =
                *reinterpret_cast<const float2*>(src + 2 * j);
        dst[6] = 0.f; dst[7] = 0.f;
    }
}

// ================= convA: conv0 + conv1 (r5 proven) ==========================
__global__ __launch_bounds__(256, 2)
void convA_kernel(const float* __restrict__ audio,
                  const float* __restrict__ W0, const float* __restrict__ b0,
                  const float* __restrict__ W1T, const float* __restrict__ b1,
                  float* __restrict__ y1g) {
    __shared__ __align__(16) float xs[244];
    __shared__ __align__(16) float y0s[64 * 124];  // 4 left pad cols

    const int tid = threadIdx.x;
    const int b = blockIdx.x;

    if (tid < 64) {
        y0s[tid * 124 + 0] = 0.f; y0s[tid * 124 + 1] = 0.f;
        y0s[tid * 124 + 2] = 0.f; y0s[tid * 124 + 3] = 0.f;
    }
    if (tid < 242) xs[tid] = (tid < 2) ? 0.f : audio[b * 240 + tid - 2];
    __syncthreads();
    {
        const int ci = tid >> 2, tg = tid & 3;
        float4 w = *reinterpret_cast<const float4*>(W0 + ci * 4);
        float bias = b0[ci];
        for (int t = tg; t < 120; t += 4) {
            float v = bias + w.x * xs[2 * t] + w.y * xs[2 * t + 1]
                           + w.z * xs[2 * t + 2] + w.w * xs[2 * t + 3];
            y0s[ci * 124 + 4 + t] = elu1(v);
        }
    }
    __syncthreads();
    {
        const int c = tid >> 1, half = tid & 1, t0 = 15 * half;
        float acc[15];
        float bias = b1[c];
#pragma unroll
        for (int u = 0; u < 15; ++u) acc[u] = bias;
        const float* wbase = W1T + c * 8;  // + ci*1024
        for (int ci = 0; ci < 64; ++ci) {
            float4 wA = *reinterpret_cast<const float4*>(wbase + ci * 1024);
            float4 wB = *reinterpret_cast<const float4*>(wbase + ci * 1024 + 4);
            const float* yb = y0s + ci * 124 + 4 * t0;
#pragma unroll
            for (int u = 0; u < 15; ++u) {
                float4 a = *reinterpret_cast<const float4*>(yb + 4 * u);
                float4 d = *reinterpret_cast<const float4*>(yb + 4 * u + 4);
                acc[u] += wA.x * a.x + wA.y * a.y + wA.z * a.z + wA.w * a.w
                        + wB.x * d.x + wB.y * d.y + wB.z * d.z + wB.w * d.w;
            }
        }
        float* yo = y1g + ((size_t)b * 128 + c) * 32 + t0;
#pragma unroll
        for (int u = 0; u < 15; ++u) yo[u] = elu1(acc[u]);
    }
}

// ================= convB v2: thread = (bi, channel-pair) =====================
// 256 thr: bi = tid>>7, cp = tid&127 -> channels cp and cp+128.
// Per ci: 8 wave-uniform ds_read_b128 (own bi only) feed 112 FMA (2 channels).
__global__ __launch_bounds__(256, 2)
void convB_kernel(const float* __restrict__ state_in,
                  const float* __restrict__ b2, const float* __restrict__ b3,
                  const float* __restrict__ W2T, const float* __restrict__ W3T,
                  const float* __restrict__ y1g,
                  float* __restrict__ out, float* __restrict__ r_ws) {
    __shared__ __align__(16) float y1s[GB * 128 * 32];
    __shared__ __align__(16) float y2s[GB * 256 * 6];

    const int tid = threadIdx.x;
    const int bbase = blockIdx.x * GB;
    const int bi = tid >> 7;     // 0..1
    const int cp = tid & 127;    // channel-pair base

    // stage y1 (col-parallel: conflict-free LDS stores, coalesced global)
    {
        const int col = tid & 31, grp = tid >> 5;
#pragma unroll
        for (int b2i = 0; b2i < GB; ++b2i) {
            const float* src = y1g + ((size_t)(bbase + b2i) * 128 + grp * 16) * 32 + col;
            float* dst = y1s + (b2i * 128 + grp * 16) * 32 + col;
#pragma unroll
            for (int i = 0; i < 16; ++i) dst[i * 32] = src[i * 32];
        }
    }
    __syncthreads();
    // ---- conv2 (128->256, k=10, s=5) + ELU ----
    {
        float accA[6], accB[6];
        const float biasA = b2[cp], biasB = b2[cp + 128];
#pragma unroll
        for (int t = 0; t < 6; ++t) { accA[t] = biasA; accB[t] = biasB; }
        const float* ybase = y1s + bi * 128 * 32;
        for (int ci = 0; ci < 128; ++ci) {
            const float* yr = ybase + ci * 32;   // wave-uniform
            float row[32];
#pragma unroll
            for (int k4 = 0; k4 < 8; ++k4) {
                float4 v = *reinterpret_cast<const float4*>(yr + k4 * 4);
                row[k4 * 4] = v.x; row[k4 * 4 + 1] = v.y;
                row[k4 * 4 + 2] = v.z; row[k4 * 4 + 3] = v.w;
            }
            const float* wpa = W2T + (ci * 256 + cp) * 12;
            float4 a0 = *reinterpret_cast<const float4*>(wpa);
            float4 a1 = *reinterpret_cast<const float4*>(wpa + 4);
            float4 a2 = *reinterpret_cast<const float4*>(wpa + 8);
            const float* wpb = wpa + 128 * 12;
            float4 c0 = *reinterpret_cast<const float4*>(wpb);
            float4 c1 = *reinterpret_cast<const float4*>(wpb + 4);
            float4 c2 = *reinterpret_cast<const float4*>(wpb + 8);
            const float wA[10] = {a0.x, a0.y, a0.z, a0.w, a1.x,
                                  a1.y, a1.z, a1.w, a2.x, a2.y};
            const float wB[10] = {c0.x, c0.y, c0.z, c0.w, c1.x,
                                  c1.y, c1.z, c1.w, c2.x, c2.y};
            // t=0: padded window, only j>=5 valid (q = j-5)
            accA[0] += wA[5] * row[0] + wA[6] * row[1] + wA[7] * row[2]
                     + wA[8] * row[3] + wA[9] * row[4];
            accB[0] += wB[5] * row[0] + wB[6] * row[1] + wB[7] * row[2]
                     + wB[8] * row[3] + wB[9] * row[4];
#pragma unroll
            for (int t = 1; t < 6; ++t) {
                const int q0 = 5 * t - 5;
                float sA = 0.f, sB = 0.f;
#pragma unroll
                for (int j = 0; j < 10; ++j) {
                    sA += wA[j] * row[q0 + j];
                    sB += wB[j] * row[q0 + j];
                }
                accA[t] += sA; accB[t] += sB;
            }
        }
        float* yoA = y2s + (bi * 256 + cp) * 6;
        float* yoB = y2s + (bi * 256 + cp + 128) * 6;
#pragma unroll
        for (int t = 0; t < 6; ++t) {
            yoA[t] = elu1(accA[t]);
            yoB[t] = elu1(accB[t]);
        }
    }
    __syncthreads();
    // ---- conv3 (256->256): taps 6..11 only; no ELU ----
    {
        float accA = b3[cp], accB = b3[cp + 128];
        const float* ybase = y2s + bi * 256 * 6;
        for (int ci = 0; ci < 256; ++ci) {
            const float* yr = ybase + ci * 6;    // wave-uniform
            float2 a = *reinterpret_cast<const float2*>(yr);
            float2 d = *reinterpret_cast<const float2*>(yr + 2);
            float2 e = *reinterpret_cast<const float2*>(yr + 4);
            const float* wpa = W3T + (ci * 256 + cp) * 8;
            float4 wa0 = *reinterpret_cast<const float4*>(wpa);
            float4 wa1 = *reinterpret_cast<const float4*>(wpa + 4);
            const float* wpb = wpa + 128 * 8;
            float4 wb0 = *reinterpret_cast<const float4*>(wpb);
            float4 wb1 = *reinterpret_cast<const float4*>(wpb + 4);
            accA += wa0.x * a.x + wa0.y * a.y + wa0.z * d.x + wa0.w * d.y
                  + wa1.x * e.x + wa1.y * e.y;
            accB += wb0.x * a.x + wb0.y * a.y + wb0.z * d.x + wb0.w * d.y
                  + wb1.x * e.x + wb1.y * e.y;
        }
        const int b = bbase + bi;
        r_ws[b * 256 + cp] = accA;
        r_ws[b * 256 + cp + 128] = accB;
        float4 siA = *reinterpret_cast<const float4*>(state_in + b * 1024 + cp * 4);
        float4 oA; oA.x = siA.y; oA.y = siA.z; oA.z = siA.w; oA.w = accA;
        *reinterpret_cast<float4*>(out + 65536 + b * 1024 + cp * 4) = oA;
        float4 siB = *reinterpret_cast<const float4*>(
            state_in + b * 1024 + (cp + 128) * 4);
        float4 oB; oB.x = siB.y; oB.y = siB.z; oB.z = siB.w; oB.w = accB;
        *reinterpret_cast<float4*>(out + 65536 + b * 1024 + (cp + 128) * 4) = oB;
    }
}

// ---------------- RVQ v6: register-direct codebook (r10 proven) --------------
__device__ __forceinline__ unsigned long long distkey(float d, int k) {
    unsigned u = __float_as_uint(d);
    u = (u & 0x80000000u) ? ~u : (u | 0x80000000u);  // monotonic float->uint
    return ((unsigned long long)u << 32) | (unsigned)k;  // low idx wins ties (np argmin)
}

__global__ __launch_bounds__(256)
void rvq_kernel(const float* __restrict__ cb, const float* __restrict__ cbT,
                const float* __restrict__ cnorm, const float* __restrict__ r_ws,
                float* __restrict__ out) {
    __shared__ __align__(16) float rs[16 * 256];  // 16 KB residuals
    __shared__ unsigned long long part_sh[2][16];
    __shared__ int idx_sh[16];

    const int tid = threadIdx.x;
    const int lane = tid & 63;
    const int wid = tid >> 6;   // 0..3
    const int bg = wid >> 1;    // 0..1: b block of 8
    const int kg = wid & 1;     // 0..1: k half of 512
    const int b0 = blockIdx.x * 16;
    const int kb = kg * 512 + 4 * lane;  // cv0 k-base (cv1 = +256)

    for (int it = 0; it < 4; ++it) {
        int o = (it * 256 + tid) * 4;
        *reinterpret_cast<float4*>(rs + o) =
            *reinterpret_cast<const float4*>(r_ws + b0 * 256 + o);
    }
    __syncthreads();

    for (int q = 0; q < 8; ++q) {
        float acc[8][8];
#pragma unroll
        for (int i = 0; i < 8; ++i)
#pragma unroll
            for (int j = 0; j < 8; ++j) acc[i][j] = 0.f;

        for (int ds = 0; ds < 32; ++ds) {
            const float* sb = cbT + (size_t)(q * 32 + ds) * 8192;
#pragma unroll
            for (int dp = 0; dp < 2; ++dp) {
                float4 cv0[4], cv1[4];
#pragma unroll
                for (int dd = 0; dd < 4; ++dd) {
                    const int dl = dp * 4 + dd;
                    cv0[dd] = *reinterpret_cast<const float4*>(sb + dl * 1024 + kb);
                    cv1[dd] = *reinterpret_cast<const float4*>(sb + dl * 1024 + kb + 256);
                }
                float rr[8][4];
#pragma unroll
                for (int i = 0; i < 8; ++i) {
                    float4 t = *reinterpret_cast<const float4*>(
                        rs + (bg * 8 + i) * 256 + ds * 8 + dp * 4);
                    rr[i][0] = t.x; rr[i][1] = t.y; rr[i][2] = t.z; rr[i][3] = t.w;
                }
#pragma unroll
                for (int dd = 0; dd < 4; ++dd) {
#pragma unroll
                    for (int i = 0; i < 8; ++i) {
                        const float r = rr[i][dd];
                        acc[i][0] += r * cv0[dd].x; acc[i][1] += r * cv0[dd].y;
                        acc[i][2] += r * cv0[dd].z; acc[i][3] += r * cv0[dd].w;
                        acc[i][4] += r * cv1[dd].x; acc[i][5] += r * cv1[dd].y;
                        acc[i][6] += r * cv1[dd].z; acc[i][7] += r * cv1[dd].w;
                    }
                }
            }
        }
        {
            float4 cn0 = *reinterpret_cast<const float4*>(cnorm + q * 1024 + kb);
            float4 cn1 = *reinterpret_cast<const float4*>(cnorm + q * 1024 + kb + 256);
            float c0e[4] = {cn0.x, cn0.y, cn0.z, cn0.w};
            float c1e[4] = {cn1.x, cn1.y, cn1.z, cn1.w};
#pragma unroll
            for (int i = 0; i < 8; ++i) {
                unsigned long long k = 0xFFFFFFFFFFFFFFFFull;
#pragma unroll
                for (int e = 0; e < 4; ++e) {
                    unsigned long long ka = distkey(c0e[e] - 2.f * acc[i][e], kb + e);
                    unsigned long long kc = distkey(c1e[e] - 2.f * acc[i][4 + e],
                                                    kb + 256 + e);
                    if (ka < k) k = ka;
                    if (kc < k) k = kc;
                }
                for (int off = 32; off >= 1; off >>= 1) {
                    unsigned long long o = __shfl_xor(k, off, 64);
                    if (o < k) k = o;
                }
                if (lane == 0) part_sh[kg][bg * 8 + i] = k;
            }
        }
        __syncthreads();
        if (tid < 16) {
            unsigned long long ka = part_sh[0][tid];
            unsigned long long kc = part_sh[1][tid];
            if (kc < ka) ka = kc;
            const int idx = (int)(ka & 0xFFFFFFFFu);
            idx_sh[tid] = idx;
            out[(b0 + tid) * 8 + q] = (float)idx;
        }
        __syncthreads();
        for (int it = 0; it < 16; ++it) {
            const int idx = idx_sh[it];
            rs[it * 256 + tid] -= cb[((size_t)(q * 1024 + idx)) * 256 + tid];
        }
        __syncthreads();
    }
}

extern "C" void kernel_launch(void* const* d_in, const int* in_sizes, int n_in,
                              void* d_out, int out_size, void* d_ws, size_t ws_size,
                              hipStream_t stream) {
    const float* audio = (const float*)d_in[0];
    const float* state = (const float*)d_in[1];
    const float* W0 = (const float*)d_in[2];
    const float* b0 = (const float*)d_in[3];
    const float* W1 = (const float*)d_in[4];
    const float* b1 = (const float*)d_in[5];
    const float* W2 = (const float*)d_in[6];
    const float* b2 = (const float*)d_in[7];
    const float* W3 = (const float*)d_in[8];
    const float* b3 = (const float*)d_in[9];
    const float* cbk = (const float*)d_in[10];
    float* out = (float*)d_out;

    float* cnorm_ws = (float*)d_ws;            // 8192
    float* r_ws = cnorm_ws + 8192;             // 2097152
    float* W1T = r_ws + 2097152;               // 65536
    float* W2T = W1T + 65536;                  // 393216 (stride 12)
    float* W3T = W2T + 393216;                 // 524288 (stride 8)
    float* y1g = W3T + 524288;                 // 33554432
    float* cbT = y1g + 33554432;               // 2097152 (8MB staged codebook)
    // total ~155 MB; ws>=196MB proven in r7

    cnorm_kernel<<<32, 256, 0, stream>>>(cbk, cnorm_ws);
    cbtrans_kernel<<<2048, 256, 0, stream>>>(cbk, cbT);
    wtrans_kernel<<<416, 256, 0, stream>>>(W1, W2, W3, W1T, W2T, W3T);
    convA_kernel<<<8192, 256, 0, stream>>>(audio, W0, b0, W1T, b1, y1g);
    convB_kernel<<<8192 / GB, 256, 0, stream>>>(state, b2, b3, W2T, W3T, y1g,
                                                out, r_ws);
    rvq_kernel<<<512, 256, 0, stream>>>(cbk, cbT, cnorm_ws, r_ws, out);
}

// Round 12
// 1871.877 us; speedup vs baseline: 1.2057x; 1.2057x over previous
//
#include <hip/hip_runtime.h>
#include <hip/hip_bf16.h>

#define GB 2  // batch elems per convB block

__device__ __forceinline__ float elu1(float v) { return v > 0.f ? v : expm1f(v); }

// ---------------- cnorm: ||cb_k||^2 per code ----------------
__global__ void cnorm_kernel(const float* __restrict__ cb, float* __restrict__ cnorm) {
    int g = blockIdx.x * blockDim.x + threadIdx.x;  // 0..8191  (q*1024+k)
    if (g >= 8 * 1024) return;
    const float* p = cb + (size_t)g * 256;
    float s = 0.f;
    for (int d = 0; d < 256; d += 4) {
        float4 v = *reinterpret_cast<const float4*>(p + d);
        s += v.x * v.x + v.y * v.y + v.z * v.z + v.w * v.w;
    }
    cnorm[g] = s;
}

// ---------------- cbtrans: codebook -> stage-major layout -------------------
// cbT[(s*8 + dl)*1024 + k] = cb[((s>>5)*1024 + k)*256 + (s&31)*8 + dl]
__global__ void cbtrans_kernel(const float* __restrict__ cb, float* __restrict__ cbT) {
    int t = blockIdx.x * blockDim.x + threadIdx.x;  // 0..524287 (float4 units)
    int o = t * 4;
    const int s = o >> 13;          // stage 0..255
    const int r = o & 8191;
    const int dl = r >> 10;
    const int k = r & 1023;         // k..k+3
    const int q = s >> 5;
    const int d = (s & 31) * 8 + dl;
    const float* src = cb + ((size_t)(q * 1024 + k)) * 256 + d;
    float4 v;
    v.x = src[0 * 256]; v.y = src[1 * 256]; v.z = src[2 * 256]; v.w = src[3 * 256];
    *reinterpret_cast<float4*>(cbT + o) = v;
}

// ---------------- weight transpose to lane-major layouts (r5 strides) -------
__global__ void wtrans_kernel(const float* __restrict__ W1, const float* __restrict__ W2,
                              const float* __restrict__ W3, float* __restrict__ W1T,
                              float* __restrict__ W2T, float* __restrict__ W3T) {
    int g = blockIdx.x * blockDim.x + threadIdx.x;
    if (g < 8192) {  // W1
        int ci = g >> 7, c = g & 127;
        const float* src = W1 + c * 512 + ci * 8;
        float4 a = *reinterpret_cast<const float4*>(src);
        float4 b = *reinterpret_cast<const float4*>(src + 4);
        *reinterpret_cast<float4*>(W1T + g * 8) = a;
        *reinterpret_cast<float4*>(W1T + g * 8 + 4) = b;
    }
    int g2 = g - 8192;
    if (g2 >= 0 && g2 < 32768) {  // W2
        int ci = g2 >> 8, c = g2 & 255;
        const float* src = W2 + c * 1280 + ci * 10;
        float* dst = W2T + g2 * 10;
#pragma unroll
        for (int j = 0; j < 5; ++j)
            *reinterpret_cast<float2*>(dst + 2 * j) =
                *reinterpret_cast<const float2*>(src + 2 * j);
    }
    int g3 = g - 40960;
    if (g3 >= 0 && g3 < 65536) {  // W3 (only taps 6..11 are ever used)
        int ci = g3 >> 8, c = g3 & 255;
        const float* src = W3 + c * 3072 + ci * 12 + 6;
        float* dst = W3T + g3 * 6;
#pragma unroll
        for (int j = 0; j < 3; ++j)
            *reinterpret_cast<float2*>(dst + 2 * j) =
                *reinterpret_cast<const float2*>(src + 2 * j);
    }
}

// ================= convA: conv0 + conv1 (r5 proven) ==========================
__global__ __launch_bounds__(256, 2)
void convA_kernel(const float* __restrict__ audio,
                  const float* __restrict__ W0, const float* __restrict__ b0,
                  const float* __restrict__ W1T, const float* __restrict__ b1,
                  float* __restrict__ y1g) {
    __shared__ __align__(16) float xs[244];
    __shared__ __align__(16) float y0s[64 * 124];  // 4 left pad cols

    const int tid = threadIdx.x;
    const int b = blockIdx.x;

    if (tid < 64) {
        y0s[tid * 124 + 0] = 0.f; y0s[tid * 124 + 1] = 0.f;
        y0s[tid * 124 + 2] = 0.f; y0s[tid * 124 + 3] = 0.f;
    }
    if (tid < 242) xs[tid] = (tid < 2) ? 0.f : audio[b * 240 + tid - 2];
    __syncthreads();
    {
        const int ci = tid >> 2, tg = tid & 3;
        float4 w = *reinterpret_cast<const float4*>(W0 + ci * 4);
        float bias = b0[ci];
        for (int t = tg; t < 120; t += 4) {
            float v = bias + w.x * xs[2 * t] + w.y * xs[2 * t + 1]
                           + w.z * xs[2 * t + 2] + w.w * xs[2 * t + 3];
            y0s[ci * 124 + 4 + t] = elu1(v);
        }
    }
    __syncthreads();
    {
        const int c = tid >> 1, half = tid & 1, t0 = 15 * half;
        float acc[15];
        float bias = b1[c];
#pragma unroll
        for (int u = 0; u < 15; ++u) acc[u] = bias;
        const float* wbase = W1T + c * 8;  // + ci*1024
        for (int ci = 0; ci < 64; ++ci) {
            float4 wA = *reinterpret_cast<const float4*>(wbase + ci * 1024);
            float4 wB = *reinterpret_cast<const float4*>(wbase + ci * 1024 + 4);
            const float* yb = y0s + ci * 124 + 4 * t0;
#pragma unroll
            for (int u = 0; u < 15; ++u) {
                float4 a = *reinterpret_cast<const float4*>(yb + 4 * u);
                float4 d = *reinterpret_cast<const float4*>(yb + 4 * u + 4);
                acc[u] += wA.x * a.x + wA.y * a.y + wA.z * a.z + wA.w * a.w
                        + wB.x * d.x + wB.y * d.y + wB.z * d.z + wB.w * d.w;
            }
        }
        float* yo = y1g + ((size_t)b * 128 + c) * 32 + t0;
#pragma unroll
        for (int u = 0; u < 15; ++u) yo[u] = elu1(acc[u]);
    }
}

// ================= convB v3: r5 body, y1 read direct from global =============
// Thread = channel c (both batches, weights amortized across GB). y1 rows are
// wave-uniform addresses -> scalar/broadcast loads from L1 (32KB tile/block).
// LDS = y2s only (12KB) -> occupancy VGPR-capped (~6-7 blocks/CU vs 3).
__global__ __launch_bounds__(256, 2)
void convB_kernel(const float* __restrict__ state_in,
                  const float* __restrict__ b2, const float* __restrict__ b3,
                  const float* __restrict__ W2T, const float* __restrict__ W3T,
                  const float* __restrict__ y1g,
                  float* __restrict__ out, float* __restrict__ r_ws) {
    __shared__ __align__(16) float y2s[GB * 256 * 6];

    const int tid = threadIdx.x;
    const int bbase = blockIdx.x * GB;

    // ---- conv2 (128->256, k=10, s=5) + ELU ----
    {
        const int c = tid;
        float acc[GB][6];
        float bias = b2[c];
#pragma unroll
        for (int bi = 0; bi < GB; ++bi)
#pragma unroll
            for (int t = 0; t < 6; ++t) acc[bi][t] = bias;
        const float* wbase = W2T + c * 10;
        for (int ci = 0; ci < 128; ++ci) {
            float w[10];
#pragma unroll
            for (int jj = 0; jj < 5; ++jj) {
                float2 wv = *reinterpret_cast<const float2*>(wbase + ci * 2560 + jj * 2);
                w[jj * 2] = wv.x; w[jj * 2 + 1] = wv.y;
            }
#pragma unroll
            for (int bi = 0; bi < GB; ++bi) {
                const float* yr = y1g + ((size_t)(bbase + bi) * 128 + ci) * 32;
                float row[32];
#pragma unroll
                for (int k4 = 0; k4 < 8; ++k4) {
                    float4 v = *reinterpret_cast<const float4*>(yr + k4 * 4);
                    row[k4 * 4] = v.x; row[k4 * 4 + 1] = v.y;
                    row[k4 * 4 + 2] = v.z; row[k4 * 4 + 3] = v.w;
                }
                acc[bi][0] += w[5] * row[0] + w[6] * row[1] + w[7] * row[2]
                            + w[8] * row[3] + w[9] * row[4];
#pragma unroll
                for (int t = 1; t < 6; ++t) {
                    const int q0 = 5 * t - 5;
                    float s = 0.f;
#pragma unroll
                    for (int j = 0; j < 10; ++j) s += w[j] * row[q0 + j];
                    acc[bi][t] += s;
                }
            }
        }
#pragma unroll
        for (int bi = 0; bi < GB; ++bi)
#pragma unroll
            for (int t = 0; t < 6; ++t)
                y2s[(bi * 256 + c) * 6 + t] = elu1(acc[bi][t]);
    }
    __syncthreads();
    // ---- conv3 (256->256): taps 6..11 only; no ELU ----
    {
        const int c = tid;
        float acc[GB];
        float bias = b3[c];
#pragma unroll
        for (int bi = 0; bi < GB; ++bi) acc[bi] = bias;
        const float* wbase = W3T + c * 6;
        for (int ci = 0; ci < 256; ++ci) {
            float2 w01 = *reinterpret_cast<const float2*>(wbase + ci * 1536);
            float2 w23 = *reinterpret_cast<const float2*>(wbase + ci * 1536 + 2);
            float2 w45 = *reinterpret_cast<const float2*>(wbase + ci * 1536 + 4);
#pragma unroll
            for (int bi = 0; bi < GB; ++bi) {
                const float* yr = y2s + (bi * 256 + ci) * 6;
                float2 a = *reinterpret_cast<const float2*>(yr);
                float2 d = *reinterpret_cast<const float2*>(yr + 2);
                float2 e = *reinterpret_cast<const float2*>(yr + 4);
                acc[bi] += w01.x * a.x + w01.y * a.y + w23.x * d.x + w23.y * d.y
                         + w45.x * e.x + w45.y * e.y;
            }
        }
#pragma unroll
        for (int bi = 0; bi < GB; ++bi) {
            const int b = bbase + bi;
            float y3 = acc[bi];
            r_ws[b * 256 + c] = y3;
            float4 si = *reinterpret_cast<const float4*>(state_in + b * 1024 + c * 4);
            float4 o; o.x = si.y; o.y = si.z; o.z = si.w; o.w = y3;
            *reinterpret_cast<float4*>(out + 65536 + b * 1024 + c * 4) = o;
        }
    }
}

// ---------------- RVQ v6: register-direct codebook (r10 proven) --------------
__device__ __forceinline__ unsigned long long distkey(float d, int k) {
    unsigned u = __float_as_uint(d);
    u = (u & 0x80000000u) ? ~u : (u | 0x80000000u);  // monotonic float->uint
    return ((unsigned long long)u << 32) | (unsigned)k;  // low idx wins ties (np argmin)
}

__global__ __launch_bounds__(256)
void rvq_kernel(const float* __restrict__ cb, const float* __restrict__ cbT,
                const float* __restrict__ cnorm, const float* __restrict__ r_ws,
                float* __restrict__ out) {
    __shared__ __align__(16) float rs[16 * 256];  // 16 KB residuals
    __shared__ unsigned long long part_sh[2][16];
    __shared__ int idx_sh[16];

    const int tid = threadIdx.x;
    const int lane = tid & 63;
    const int wid = tid >> 6;   // 0..3
    const int bg = wid >> 1;    // 0..1: b block of 8
    const int kg = wid & 1;     // 0..1: k half of 512
    const int b0 = blockIdx.x * 16;
    const int kb = kg * 512 + 4 * lane;  // cv0 k-base (cv1 = +256)

    for (int it = 0; it < 4; ++it) {
        int o = (it * 256 + tid) * 4;
        *reinterpret_cast<float4*>(rs + o) =
            *reinterpret_cast<const float4*>(r_ws + b0 * 256 + o);
    }
    __syncthreads();

    for (int q = 0; q < 8; ++q) {
        float acc[8][8];
#pragma unroll
        for (int i = 0; i < 8; ++i)
#pragma unroll
            for (int j = 0; j < 8; ++j) acc[i][j] = 0.f;

        for (int ds = 0; ds < 32; ++ds) {
            const float* sb = cbT + (size_t)(q * 32 + ds) * 8192;
#pragma unroll
            for (int dp = 0; dp < 2; ++dp) {
                float4 cv0[4], cv1[4];
#pragma unroll
                for (int dd = 0; dd < 4; ++dd) {
                    const int dl = dp * 4 + dd;
                    cv0[dd] = *reinterpret_cast<const float4*>(sb + dl * 1024 + kb);
                    cv1[dd] = *reinterpret_cast<const float4*>(sb + dl * 1024 + kb + 256);
                }
                float rr[8][4];
#pragma unroll
                for (int i = 0; i < 8; ++i) {
                    float4 t = *reinterpret_cast<const float4*>(
                        rs + (bg * 8 + i) * 256 + ds * 8 + dp * 4);
                    rr[i][0] = t.x; rr[i][1] = t.y; rr[i][2] = t.z; rr[i][3] = t.w;
                }
#pragma unroll
                for (int dd = 0; dd < 4; ++dd) {
#pragma unroll
                    for (int i = 0; i < 8; ++i) {
                        const float r = rr[i][dd];
                        acc[i][0] += r * cv0[dd].x; acc[i][1] += r * cv0[dd].y;
                        acc[i][2] += r * cv0[dd].z; acc[i][3] += r * cv0[dd].w;
                        acc[i][4] += r * cv1[dd].x; acc[i][5] += r * cv1[dd].y;
                        acc[i][6] += r * cv1[dd].z; acc[i][7] += r * cv1[dd].w;
                    }
                }
            }
        }
        {
            float4 cn0 = *reinterpret_cast<const float4*>(cnorm + q * 1024 + kb);
            float4 cn1 = *reinterpret_cast<const float4*>(cnorm + q * 1024 + kb + 256);
            float c0e[4] = {cn0.x, cn0.y, cn0.z, cn0.w};
            float c1e[4] = {cn1.x, cn1.y, cn1.z, cn1.w};
#pragma unroll
            for (int i = 0; i < 8; ++i) {
                unsigned long long k = 0xFFFFFFFFFFFFFFFFull;
#pragma unroll
                for (int e = 0; e < 4; ++e) {
                    unsigned long long ka = distkey(c0e[e] - 2.f * acc[i][e], kb + e);
                    unsigned long long kc = distkey(c1e[e] - 2.f * acc[i][4 + e],
                                                    kb + 256 + e);
                    if (ka < k) k = ka;
                    if (kc < k) k = kc;
                }
                for (int off = 32; off >= 1; off >>= 1) {
                    unsigned long long o = __shfl_xor(k, off, 64);
                    if (o < k) k = o;
                }
                if (lane == 0) part_sh[kg][bg * 8 + i] = k;
            }
        }
        __syncthreads();
        if (tid < 16) {
            unsigned long long ka = part_sh[0][tid];
            unsigned long long kc = part_sh[1][tid];
            if (kc < ka) ka = kc;
            const int idx = (int)(ka & 0xFFFFFFFFu);
            idx_sh[tid] = idx;
            out[(b0 + tid) * 8 + q] = (float)idx;
        }
        __syncthreads();
        for (int it = 0; it < 16; ++it) {
            const int idx = idx_sh[it];
            rs[it * 256 + tid] -= cb[((size_t)(q * 1024 + idx)) * 256 + tid];
        }
        __syncthreads();
    }
}

extern "C" void kernel_launch(void* const* d_in, const int* in_sizes, int n_in,
                              void* d_out, int out_size, void* d_ws, size_t ws_size,
                              hipStream_t stream) {
    const float* audio = (const float*)d_in[0];
    const float* state = (const float*)d_in[1];
    const float* W0 = (const float*)d_in[2];
    const float* b0 = (const float*)d_in[3];
    const float* W1 = (const float*)d_in[4];
    const float* b1 = (const float*)d_in[5];
    const float* W2 = (const float*)d_in[6];
    const float* b2 = (const float*)d_in[7];
    const float* W3 = (const float*)d_in[8];
    const float* b3 = (const float*)d_in[9];
    const float* cbk = (const float*)d_in[10];
    float* out = (float*)d_out;

    float* cnorm_ws = (float*)d_ws;            // 8192
    float* r_ws = cnorm_ws + 8192;             // 2097152
    float* W1T = r_ws + 2097152;               // 65536
    float* W2T = W1T + 65536;                  // 327680 (stride 10)
    float* W3T = W2T + 327680;                 // 393216 (stride 6)
    float* y1g = W3T + 393216;                 // 33554432
    float* cbT = y1g + 33554432;               // 2097152 (8MB staged codebook)
    // total ~154 MB; ws>=196MB proven in r7

    cnorm_kernel<<<32, 256, 0, stream>>>(cbk, cnorm_ws);
    cbtrans_kernel<<<2048, 256, 0, stream>>>(cbk, cbT);
    wtrans_kernel<<<416, 256, 0, stream>>>(W1, W2, W3, W1T, W2T, W3T);
    convA_kernel<<<8192, 256, 0, stream>>>(audio, W0, b0, W1T, b1, y1g);
    convB_kernel<<<8192 / GB, 256, 0, stream>>>(state, b2, b3, W2T, W3T, y1g,
                                                out, r_ws);
    rvq_kernel<<<512, 256, 0, stream>>>(cbk, cbT, cnorm_ws, r_ws, out);
}

// Round 13
// 1862.837 us; speedup vs baseline: 1.2115x; 1.0049x over previous
//
#include <hip/hip_runtime.h>
#include <hip/hip_bf16.h>

#define GB 2  // batch elems per convB block

__device__ __forceinline__ float elu1(float v) { return v > 0.f ? v : expm1f(v); }

// ---------------- cnorm: ||cb_k||^2 per code ----------------
__global__ void cnorm_kernel(const float* __restrict__ cb, float* __restrict__ cnorm) {
    int g = blockIdx.x * blockDim.x + threadIdx.x;  // 0..8191  (q*1024+k)
    if (g >= 8 * 1024) return;
    const float* p = cb + (size_t)g * 256;
    float s = 0.f;
    for (int d = 0; d < 256; d += 4) {
        float4 v = *reinterpret_cast<const float4*>(p + d);
        s += v.x * v.x + v.y * v.y + v.z * v.z + v.w * v.w;
    }
    cnorm[g] = s;
}

// ---------------- cbtrans: codebook -> stage-major layout -------------------
// cbT[(s*8 + dl)*1024 + k] = cb[((s>>5)*1024 + k)*256 + (s&31)*8 + dl]
__global__ void cbtrans_kernel(const float* __restrict__ cb, float* __restrict__ cbT) {
    int t = blockIdx.x * blockDim.x + threadIdx.x;  // 0..524287 (float4 units)
    int o = t * 4;
    const int s = o >> 13;          // stage 0..255
    const int r = o & 8191;
    const int dl = r >> 10;
    const int k = r & 1023;         // k..k+3
    const int q = s >> 5;
    const int d = (s & 31) * 8 + dl;
    const float* src = cb + ((size_t)(q * 1024 + k)) * 256 + d;
    float4 v;
    v.x = src[0 * 256]; v.y = src[1 * 256]; v.z = src[2 * 256]; v.w = src[3 * 256];
    *reinterpret_cast<float4*>(cbT + o) = v;
}

// ---------------- weight transpose to lane-major layouts (r5 strides) -------
__global__ void wtrans_kernel(const float* __restrict__ W1, const float* __restrict__ W2,
                              const float* __restrict__ W3, float* __restrict__ W1T,
                              float* __restrict__ W2T, float* __restrict__ W3T) {
    int g = blockIdx.x * blockDim.x + threadIdx.x;
    if (g < 8192) {  // W1
        int ci = g >> 7, c = g & 127;
        const float* src = W1 + c * 512 + ci * 8;
        float4 a = *reinterpret_cast<const float4*>(src);
        float4 b = *reinterpret_cast<const float4*>(src + 4);
        *reinterpret_cast<float4*>(W1T + g * 8) = a;
        *reinterpret_cast<float4*>(W1T + g * 8 + 4) = b;
    }
    int g2 = g - 8192;
    if (g2 >= 0 && g2 < 32768) {  // W2
        int ci = g2 >> 8, c = g2 & 255;
        const float* src = W2 + c * 1280 + ci * 10;
        float* dst = W2T + g2 * 10;
#pragma unroll
        for (int j = 0; j < 5; ++j)
            *reinterpret_cast<float2*>(dst + 2 * j) =
                *reinterpret_cast<const float2*>(src + 2 * j);
    }
    int g3 = g - 40960;
    if (g3 >= 0 && g3 < 65536) {  // W3 (only taps 6..11 are ever used)
        int ci = g3 >> 8, c = g3 & 255;
        const float* src = W3 + c * 3072 + ci * 12 + 6;
        float* dst = W3T + g3 * 6;
#pragma unroll
        for (int j = 0; j < 3; ++j)
            *reinterpret_cast<float2*>(dst + 2 * j) =
                *reinterpret_cast<const float2*>(src + 2 * j);
    }
}

// ================= convA v2: conv0 + conv1 with row-register conv1 ==========
// conv1 per ci: 16 contiguous b128 LDS loads upfront (one wait), then 120 FMA
// with static row4 indexing (d(u)==a(u+1) CSE). Replaces the 30-read
// interleaved chain that exposed LDS latency every 8 FMAs (r12: 966cy/ci).
__global__ __launch_bounds__(256, 2)
void convA_kernel(const float* __restrict__ audio,
                  const float* __restrict__ W0, const float* __restrict__ b0,
                  const float* __restrict__ W1T, const float* __restrict__ b1,
                  float* __restrict__ y1g) {
    __shared__ __align__(16) float xs[244];
    __shared__ __align__(16) float y0s[64 * 124];  // 4 left pad cols

    const int tid = threadIdx.x;
    const int b = blockIdx.x;

    if (tid < 64) {
        y0s[tid * 124 + 0] = 0.f; y0s[tid * 124 + 1] = 0.f;
        y0s[tid * 124 + 2] = 0.f; y0s[tid * 124 + 3] = 0.f;
    }
    if (tid < 242) xs[tid] = (tid < 2) ? 0.f : audio[b * 240 + tid - 2];
    __syncthreads();
    // ---- conv0 (1->64, k=4, s=2) + ELU ----
    {
        const int ci = tid >> 2, tg = tid & 3;
        float4 w = *reinterpret_cast<const float4*>(W0 + ci * 4);
        float bias = b0[ci];
        for (int t = tg; t < 120; t += 4) {
            float v = bias + w.x * xs[2 * t] + w.y * xs[2 * t + 1]
                           + w.z * xs[2 * t + 2] + w.w * xs[2 * t + 3];
            y0s[ci * 124 + 4 + t] = elu1(v);
        }
    }
    __syncthreads();
    // ---- conv1 (64->128, k=8, s=4) + ELU ----
    {
        const int c = tid >> 1, half = tid & 1, t0 = 15 * half;
        float acc[15];
        float bias = b1[c];
#pragma unroll
        for (int u = 0; u < 15; ++u) acc[u] = bias;
        const float* wbase = W1T + c * 8;        // + ci*1024
        const float* ybase = y0s + 4 * t0;       // + ci*124
        for (int ci = 0; ci < 64; ++ci) {
            float4 wA = *reinterpret_cast<const float4*>(wbase + ci * 1024);
            float4 wB = *reinterpret_cast<const float4*>(wbase + ci * 1024 + 4);
            const float* yb = ybase + ci * 124;
            float4 row4[16];
#pragma unroll
            for (int j = 0; j < 16; ++j)
                row4[j] = *reinterpret_cast<const float4*>(yb + 4 * j);
#pragma unroll
            for (int u = 0; u < 15; ++u) {
                acc[u] += wA.x * row4[u].x + wA.y * row4[u].y
                        + wA.z * row4[u].z + wA.w * row4[u].w
                        + wB.x * row4[u + 1].x + wB.y * row4[u + 1].y
                        + wB.z * row4[u + 1].z + wB.w * row4[u + 1].w;
            }
        }
        float* yo = y1g + ((size_t)b * 128 + c) * 32 + t0;
#pragma unroll
        for (int u = 0; u < 15; ++u) yo[u] = elu1(acc[u]);
    }
}

// ================= convB v3 (r12 proven): y1 direct from global ==============
__global__ __launch_bounds__(256, 2)
void convB_kernel(const float* __restrict__ state_in,
                  const float* __restrict__ b2, const float* __restrict__ b3,
                  const float* __restrict__ W2T, const float* __restrict__ W3T,
                  const float* __restrict__ y1g,
                  float* __restrict__ out, float* __restrict__ r_ws) {
    __shared__ __align__(16) float y2s[GB * 256 * 6];

    const int tid = threadIdx.x;
    const int bbase = blockIdx.x * GB;

    // ---- conv2 (128->256, k=10, s=5) + ELU ----
    {
        const int c = tid;
        float acc[GB][6];
        float bias = b2[c];
#pragma unroll
        for (int bi = 0; bi < GB; ++bi)
#pragma unroll
            for (int t = 0; t < 6; ++t) acc[bi][t] = bias;
        const float* wbase = W2T + c * 10;
        for (int ci = 0; ci < 128; ++ci) {
            float w[10];
#pragma unroll
            for (int jj = 0; jj < 5; ++jj) {
                float2 wv = *reinterpret_cast<const float2*>(wbase + ci * 2560 + jj * 2);
                w[jj * 2] = wv.x; w[jj * 2 + 1] = wv.y;
            }
#pragma unroll
            for (int bi = 0; bi < GB; ++bi) {
                const float* yr = y1g + ((size_t)(bbase + bi) * 128 + ci) * 32;
                float row[32];
#pragma unroll
                for (int k4 = 0; k4 < 8; ++k4) {
                    float4 v = *reinterpret_cast<const float4*>(yr + k4 * 4);
                    row[k4 * 4] = v.x; row[k4 * 4 + 1] = v.y;
                    row[k4 * 4 + 2] = v.z; row[k4 * 4 + 3] = v.w;
                }
                acc[bi][0] += w[5] * row[0] + w[6] * row[1] + w[7] * row[2]
                            + w[8] * row[3] + w[9] * row[4];
#pragma unroll
                for (int t = 1; t < 6; ++t) {
                    const int q0 = 5 * t - 5;
                    float s = 0.f;
#pragma unroll
                    for (int j = 0; j < 10; ++j) s += w[j] * row[q0 + j];
                    acc[bi][t] += s;
                }
            }
        }
#pragma unroll
        for (int bi = 0; bi < GB; ++bi)
#pragma unroll
            for (int t = 0; t < 6; ++t)
                y2s[(bi * 256 + c) * 6 + t] = elu1(acc[bi][t]);
    }
    __syncthreads();
    // ---- conv3 (256->256): taps 6..11 only; no ELU ----
    {
        const int c = tid;
        float acc[GB];
        float bias = b3[c];
#pragma unroll
        for (int bi = 0; bi < GB; ++bi) acc[bi] = bias;
        const float* wbase = W3T + c * 6;
        for (int ci = 0; ci < 256; ++ci) {
            float2 w01 = *reinterpret_cast<const float2*>(wbase + ci * 1536);
            float2 w23 = *reinterpret_cast<const float2*>(wbase + ci * 1536 + 2);
            float2 w45 = *reinterpret_cast<const float2*>(wbase + ci * 1536 + 4);
#pragma unroll
            for (int bi = 0; bi < GB; ++bi) {
                const float* yr = y2s + (bi * 256 + ci) * 6;
                float2 a = *reinterpret_cast<const float2*>(yr);
                float2 d = *reinterpret_cast<const float2*>(yr + 2);
                float2 e = *reinterpret_cast<const float2*>(yr + 4);
                acc[bi] += w01.x * a.x + w01.y * a.y + w23.x * d.x + w23.y * d.y
                         + w45.x * e.x + w45.y * e.y;
            }
        }
#pragma unroll
        for (int bi = 0; bi < GB; ++bi) {
            const int b = bbase + bi;
            float y3 = acc[bi];
            r_ws[b * 256 + c] = y3;
            float4 si = *reinterpret_cast<const float4*>(state_in + b * 1024 + c * 4);
            float4 o; o.x = si.y; o.y = si.z; o.z = si.w; o.w = y3;
            *reinterpret_cast<float4*>(out + 65536 + b * 1024 + c * 4) = o;
        }
    }
}

// ---------------- RVQ v6: register-direct codebook (r10 proven) --------------
__device__ __forceinline__ unsigned long long distkey(float d, int k) {
    unsigned u = __float_as_uint(d);
    u = (u & 0x80000000u) ? ~u : (u | 0x80000000u);  // monotonic float->uint
    return ((unsigned long long)u << 32) | (unsigned)k;  // low idx wins ties (np argmin)
}

__global__ __launch_bounds__(256)
void rvq_kernel(const float* __restrict__ cb, const float* __restrict__ cbT,
                const float* __restrict__ cnorm, const float* __restrict__ r_ws,
                float* __restrict__ out) {
    __shared__ __align__(16) float rs[16 * 256];  // 16 KB residuals
    __shared__ unsigned long long part_sh[2][16];
    __shared__ int idx_sh[16];

    const int tid = threadIdx.x;
    const int lane = tid & 63;
    const int wid = tid >> 6;   // 0..3
    const int bg = wid >> 1;    // 0..1: b block of 8
    const int kg = wid & 1;     // 0..1: k half of 512
    const int b0 = blockIdx.x * 16;
    const int kb = kg * 512 + 4 * lane;  // cv0 k-base (cv1 = +256)

    for (int it = 0; it < 4; ++it) {
        int o = (it * 256 + tid) * 4;
        *reinterpret_cast<float4*>(rs + o) =
            *reinterpret_cast<const float4*>(r_ws + b0 * 256 + o);
    }
    __syncthreads();

    for (int q = 0; q < 8; ++q) {
        float acc[8][8];
#pragma unroll
        for (int i = 0; i < 8; ++i)
#pragma unroll
            for (int j = 0; j < 8; ++j) acc[i][j] = 0.f;

        for (int ds = 0; ds < 32; ++ds) {
            const float* sb = cbT + (size_t)(q * 32 + ds) * 8192;
#pragma unroll
            for (int dp = 0; dp < 2; ++dp) {
                float4 cv0[4], cv1[4];
#pragma unroll
                for (int dd = 0; dd < 4; ++dd) {
                    const int dl = dp * 4 + dd;
                    cv0[dd] = *reinterpret_cast<const float4*>(sb + dl * 1024 + kb);
                    cv1[dd] = *reinterpret_cast<const float4*>(sb + dl * 1024 + kb + 256);
                }
                float rr[8][4];
#pragma unroll
                for (int i = 0; i < 8; ++i) {
                    float4 t = *reinterpret_cast<const float4*>(
                        rs + (bg * 8 + i) * 256 + ds * 8 + dp * 4);
                    rr[i][0] = t.x; rr[i][1] = t.y; rr[i][2] = t.z; rr[i][3] = t.w;
                }
#pragma unroll
                for (int dd = 0; dd < 4; ++dd) {
#pragma unroll
                    for (int i = 0; i < 8; ++i) {
                        const float r = rr[i][dd];
                        acc[i][0] += r * cv0[dd].x; acc[i][1] += r * cv0[dd].y;
                        acc[i][2] += r * cv0[dd].z; acc[i][3] += r * cv0[dd].w;
                        acc[i][4] += r * cv1[dd].x; acc[i][5] += r * cv1[dd].y;
                        acc[i][6] += r * cv1[dd].z; acc[i][7] += r * cv1[dd].w;
                    }
                }
            }
        }
        {
            float4 cn0 = *reinterpret_cast<const float4*>(cnorm + q * 1024 + kb);
            float4 cn1 = *reinterpret_cast<const float4*>(cnorm + q * 1024 + kb + 256);
            float c0e[4] = {cn0.x, cn0.y, cn0.z, cn0.w};
            float c1e[4] = {cn1.x, cn1.y, cn1.z, cn1.w};
#pragma unroll
            for (int i = 0; i < 8; ++i) {
                unsigned long long k = 0xFFFFFFFFFFFFFFFFull;
#pragma unroll
                for (int e = 0; e < 4; ++e) {
                    unsigned long long ka = distkey(c0e[e] - 2.f * acc[i][e], kb + e);
                    unsigned long long kc = distkey(c1e[e] - 2.f * acc[i][4 + e],
                                                    kb + 256 + e);
                    if (ka < k) k = ka;
                    if (kc < k) k = kc;
                }
                for (int off = 32; off >= 1; off >>= 1) {
                    unsigned long long o = __shfl_xor(k, off, 64);
                    if (o < k) k = o;
                }
                if (lane == 0) part_sh[kg][bg * 8 + i] = k;
            }
        }
        __syncthreads();
        if (tid < 16) {
            unsigned long long ka = part_sh[0][tid];
            unsigned long long kc = part_sh[1][tid];
            if (kc < ka) ka = kc;
            const int idx = (int)(ka & 0xFFFFFFFFu);
            idx_sh[tid] = idx;
            out[(b0 + tid) * 8 + q] = (float)idx;
        }
        __syncthreads();
        for (int it = 0; it < 16; ++it) {
            const int idx = idx_sh[it];
            rs[it * 256 + tid] -= cb[((size_t)(q * 1024 + idx)) * 256 + tid];
        }
        __syncthreads();
    }
}

extern "C" void kernel_launch(void* const* d_in, const int* in_sizes, int n_in,
                              void* d_out, int out_size, void* d_ws, size_t ws_size,
                              hipStream_t stream) {
    const float* audio = (const float*)d_in[0];
    const float* state = (const float*)d_in[1];
    const float* W0 = (const float*)d_in[2];
    const float* b0 = (const float*)d_in[3];
    const float* W1 = (const float*)d_in[4];
    const float* b1 = (const float*)d_in[5];
    const float* W2 = (const float*)d_in[6];
    const float* b2 = (const float*)d_in[7];
    const float* W3 = (const float*)d_in[8];
    const float* b3 = (const float*)d_in[9];
    const float* cbk = (const float*)d_in[10];
    float* out = (float*)d_out;

    float* cnorm_ws = (float*)d_ws;            // 8192
    float* r_ws = cnorm_ws + 8192;             // 2097152
    float* W1T = r_ws + 2097152;               // 65536
    float* W2T = W1T + 65536;                  // 327680 (stride 10)
    float* W3T = W2T + 327680;                 // 393216 (stride 6)
    float* y1g = W3T + 393216;                 // 33554432
    float* cbT = y1g + 33554432;               // 2097152 (8MB staged codebook)
    // total ~154 MB; ws>=196MB proven in r7

    cnorm_kernel<<<32, 256, 0, stream>>>(cbk, cnorm_ws);
    cbtrans_kernel<<<2048, 256, 0, stream>>>(cbk, cbT);
    wtrans_kernel<<<416, 256, 0, stream>>>(W1, W2, W3, W1T, W2T, W3T);
    convA_kernel<<<8192, 256, 0, stream>>>(audio, W0, b0, W1T, b1, y1g);
    convB_kernel<<<8192 / GB, 256, 0, stream>>>(state, b2, b3, W2T, W3T, y1g,
                                                out, r_ws);
    rvq_kernel<<<512, 256, 0, stream>>>(cbk, cbT, cnorm_ws, r_ws, out);
}